// Round 1
// baseline (1407.928 us; speedup 1.0000x reference)
//
#include <hip/hip_runtime.h>

#define DIV_UP(a,b) (((a)+(b)-1)/(b))

__device__ __forceinline__ float silu_f(float x) {
    return x / (1.0f + __expf(-x));
}

// ---------------------------------------------------------------------------
// Edge geometry: dist -> rbf[E][16], env[E].  sin(n x) via Chebyshev recurrence.
// ---------------------------------------------------------------------------
__global__ __launch_bounds__(256) void edge_geom_kernel(
    const int* __restrict__ nbr, const float* __restrict__ xyz,
    float* __restrict__ rbf, float* __restrict__ env, int E)
{
    int e = blockIdx.x * 256 + threadIdx.x;
    if (e >= E) return;
    int i = nbr[2 * e], j = nbr[2 * e + 1];
    float dx = xyz[3 * j + 0] - xyz[3 * i + 0];
    float dy = xyz[3 * j + 1] - xyz[3 * i + 1];
    float dz = xyz[3 * j + 2] - xyz[3 * i + 2];
    float dist = sqrtf(dx * dx + dy * dy + dz * dz);
    float x = dist * 0.3141592653589793f;   // pi/CUTOFF
    float s, c;
    __sincosf(x, &s, &c);
    float inv = 1.0f / dist;
    float two_c = 2.0f * c;
    float sm1 = 0.0f, s0 = s;
    float out[16];
    #pragma unroll
    for (int k = 0; k < 16; ++k) {
        out[k] = s0 * inv;
        float s1 = two_c * s0 - sm1;
        sm1 = s0; s0 = s1;
    }
    float4* rp = (float4*)(rbf + (size_t)e * 16);
    rp[0] = make_float4(out[0],  out[1],  out[2],  out[3]);
    rp[1] = make_float4(out[4],  out[5],  out[6],  out[7]);
    rp[2] = make_float4(out[8],  out[9],  out[10], out[11]);
    rp[3] = make_float4(out[12], out[13], out[14], out[15]);
    env[e] = (dist < 10.0f) ? 0.5f * (c + 1.0f) : 0.0f;
}

// ---------------------------------------------------------------------------
// S0 = concat(S[N,124], res_embed[cg_z][N,4])  -> [N,128]
// ---------------------------------------------------------------------------
__global__ __launch_bounds__(256) void concat_s_kernel(
    const float* __restrict__ S, const float* __restrict__ res_embed,
    const int* __restrict__ z, float* __restrict__ S0, int N)
{
    int idx = blockIdx.x * 256 + threadIdx.x;
    if (idx >= N * 128) return;
    int n = idx >> 7, c = idx & 127;
    float val = (c < 124) ? S[n * 124 + c] : res_embed[z[n] * 4 + (c - 124)];
    S0[idx] = val;
}

// ---------------------------------------------------------------------------
// scS = concat(S0[N,128], scA[N,10]) -> [N,140] (2 pad zeros)
// ---------------------------------------------------------------------------
__global__ __launch_bounds__(256) void concat_sc_kernel(
    const float* __restrict__ S0, const float* __restrict__ scA,
    float* __restrict__ scS, int N)
{
    int idx = blockIdx.x * 256 + threadIdx.x;
    if (idx >= N * 140) return;
    int n = idx / 140, c = idx - n * 140;
    float val = 0.0f;
    if (c < 128)       val = S0[n * 128 + c];
    else if (c < 138)  val = scA[n * 10 + (c - 128)];
    scS[idx] = val;
}

// ---------------------------------------------------------------------------
// Generic two-stage MLP over rows:
//   Y[row] (+=) ( silu( f_in(X[row]) @ W1 + b1 ) @ W2 + b2 )
// f_in = silu if PREACT. K = 128 or 138, square weights (K x K).
// 48 rows per block staged in LDS; 256 threads; thread tile = 6 rows x NC cols.
// ---------------------------------------------------------------------------
template<int K, bool PREACT, bool RESID>
__global__ __launch_bounds__(256) void mlp2_kernel(
    const float* __restrict__ X, int ldX,
    const float* __restrict__ W1, const float* __restrict__ b1,
    const float* __restrict__ W2, const float* __restrict__ b2,
    float* __restrict__ Y, int ldY, int nrows)
{
    constexpr int NC = (K + 31) / 32;   // 4 (K=128) or 5 (K=138)
    constexpr int ROWS = 48;
    constexpr int RR = 6;
    __shared__ float Xs[ROWS * K];
    __shared__ float Hs[ROWS * K];
    const int tid = threadIdx.x;
    const int row0 = blockIdx.x * ROWS;

    for (int idx = tid; idx < ROWS * K; idx += 256) {
        int r = idx / K, c = idx - r * K;
        int gr = row0 + r;
        float x = (gr < nrows) ? X[(size_t)gr * ldX + c] : 0.0f;
        if (PREACT) x = silu_f(x);
        Xs[idx] = x;
    }
    __syncthreads();

    const int cc = tid & 31;
    const int r0 = (tid >> 5) * RR;

    float acc[NC][RR];
    #pragma unroll
    for (int jc = 0; jc < NC; ++jc) {
        int col = cc + 32 * jc;
        float bv = (col < K) ? b1[col] : 0.0f;
        #pragma unroll
        for (int rr = 0; rr < RR; ++rr) acc[jc][rr] = bv;
    }
    for (int k = 0; k < K; ++k) {
        float w[NC];
        #pragma unroll
        for (int jc = 0; jc < NC; ++jc) {
            int col = cc + 32 * jc;
            w[jc] = (col < K) ? W1[k * K + col] : 0.0f;
        }
        float xv[RR];
        #pragma unroll
        for (int rr = 0; rr < RR; ++rr) xv[rr] = Xs[(r0 + rr) * K + k];
        #pragma unroll
        for (int jc = 0; jc < NC; ++jc)
            #pragma unroll
            for (int rr = 0; rr < RR; ++rr)
                acc[jc][rr] = fmaf(xv[rr], w[jc], acc[jc][rr]);
    }
    #pragma unroll
    for (int jc = 0; jc < NC; ++jc) {
        int col = cc + 32 * jc;
        if (col < K) {
            #pragma unroll
            for (int rr = 0; rr < RR; ++rr)
                Hs[(r0 + rr) * K + col] = silu_f(acc[jc][rr]);
        }
    }
    __syncthreads();

    #pragma unroll
    for (int jc = 0; jc < NC; ++jc) {
        int col = cc + 32 * jc;
        float bv = (col < K) ? b2[col] : 0.0f;
        #pragma unroll
        for (int rr = 0; rr < RR; ++rr) acc[jc][rr] = bv;
    }
    for (int k = 0; k < K; ++k) {
        float w[NC];
        #pragma unroll
        for (int jc = 0; jc < NC; ++jc) {
            int col = cc + 32 * jc;
            w[jc] = (col < K) ? W2[k * K + col] : 0.0f;
        }
        float xv[RR];
        #pragma unroll
        for (int rr = 0; rr < RR; ++rr) xv[rr] = Hs[(r0 + rr) * K + k];
        #pragma unroll
        for (int jc = 0; jc < NC; ++jc)
            #pragma unroll
            for (int rr = 0; rr < RR; ++rr)
                acc[jc][rr] = fmaf(xv[rr], w[jc], acc[jc][rr]);
    }
    #pragma unroll
    for (int jc = 0; jc < NC; ++jc) {
        int col = cc + 32 * jc;
        if (col < K) {
            #pragma unroll
            for (int rr = 0; rr < RR; ++rr) {
                int gr = row0 + r0 + rr;
                if (gr < nrows) {
                    size_t off = (size_t)gr * ldY + col;
                    float val = acc[jc][rr];
                    if (RESID) val += Y[off];
                    Y[off] = val;
                }
            }
        }
    }
}

// ---------------------------------------------------------------------------
// Edge message + segment sum (atomic):
//   w_s = (rbf[e] @ distW + distb) * env[e];  v[i] += phi[j] * w_s
// distW (16x128) held in registers per thread (its 4 column slots).
// 8 edges per 256-thread block iteration, grid-stride.
// ---------------------------------------------------------------------------
__global__ __launch_bounds__(256) void edge_msg_kernel(
    const int* __restrict__ nbr, const float* __restrict__ rbf,
    const float* __restrict__ env, const float* __restrict__ phi,
    const float* __restrict__ distW, const float* __restrict__ distb,
    float* __restrict__ v, int E)
{
    const int lane = threadIdx.x & 31;
    const int grp = threadIdx.x >> 5;
    float dw[64];
    #pragma unroll
    for (int k = 0; k < 16; ++k)
        #pragma unroll
        for (int jc = 0; jc < 4; ++jc)
            dw[k * 4 + jc] = distW[k * 128 + lane + 32 * jc];
    float db[4];
    #pragma unroll
    for (int jc = 0; jc < 4; ++jc) db[jc] = distb[lane + 32 * jc];

    const int stride = gridDim.x * 8;
    for (int e = blockIdx.x * 8 + grp; e < E; e += stride) {
        int i = nbr[2 * e], j = nbr[2 * e + 1];
        float ev = env[e];
        const float* rb = rbf + (size_t)e * 16;
        float r[16];
        #pragma unroll
        for (int k = 0; k < 16; ++k) r[k] = rb[k];
        const float* pj = phi + (size_t)j * 128;
        float* vi = v + (size_t)i * 128;
        #pragma unroll
        for (int jc = 0; jc < 4; ++jc) {
            float acc = db[jc];
            #pragma unroll
            for (int k = 0; k < 16; ++k)
                acc = fmaf(r[k], dw[k * 4 + jc], acc);
            acc *= ev;
            float m = pj[lane + 32 * jc] * acc;
            atomicAdd(vi + lane + 32 * jc, m);
        }
    }
}

// ---------------------------------------------------------------------------
// Small head: out = silu( silu(x) @ W1 + b1 ) @ W2 + b2   (final linear, no act)
// x = concat(X[n, :K1], X2[n, :K2]).  One wave per node, M = 3 or 10.
// ---------------------------------------------------------------------------
template<int M>
__global__ __launch_bounds__(256) void head_kernel(
    const float* __restrict__ X, int ldX, int K1,
    const float* __restrict__ X2, int ldX2, int K2,
    const float* __restrict__ W1, const float* __restrict__ b1,
    const float* __restrict__ W2, const float* __restrict__ b2,
    float* __restrict__ out, int ldOut, int nrows)
{
    const int wid = threadIdx.x >> 6;
    const int lane = threadIdx.x & 63;
    const int n = blockIdx.x * 4 + wid;
    if (n >= nrows) return;
    const int K = K1 + K2;
    float sx[3];
    #pragma unroll
    for (int t = 0; t < 3; ++t) {
        int k = lane + 64 * t;
        float v = 0.0f;
        if (k < K1) v = X[(size_t)n * ldX + k];
        else if (k < K) v = X2[(size_t)n * ldX2 + (k - K1)];
        sx[t] = (k < K) ? silu_f(v) : 0.0f;
    }
    float acc[M];
    #pragma unroll
    for (int m = 0; m < M; ++m) {
        float a = 0.0f;
        #pragma unroll
        for (int t = 0; t < 3; ++t) {
            int k = lane + 64 * t;
            if (k < K) a = fmaf(sx[t], W1[k * M + m], a);
        }
        acc[m] = a;
    }
    #pragma unroll
    for (int m = 0; m < M; ++m) {
        #pragma unroll
        for (int off = 32; off > 0; off >>= 1)
            acc[m] += __shfl_xor(acc[m], off, 64);
    }
    float tm[M];
    #pragma unroll
    for (int m = 0; m < M; ++m) tm[m] = silu_f(acc[m] + b1[m]);
    if (lane < M) {
        float o = b2[lane];
        #pragma unroll
        for (int m = 0; m < M; ++m) o = fmaf(tm[m], W2[m * M + lane], o);
        out[(size_t)n * ldOut + lane] = o;
    }
}

// ---------------------------------------------------------------------------
// Output assembly: out[N][13][3]
// ---------------------------------------------------------------------------
__global__ __launch_bounds__(256) void assemble_kernel(
    const int* __restrict__ z,
    const float* __restrict__ bbde, const float* __restrict__ scde,
    const float* __restrict__ bbA, const float* __restrict__ bbT,
    const float* __restrict__ scA, const float* __restrict__ scT,
    float* __restrict__ out, int N)
{
    int idx = blockIdx.x * 256 + threadIdx.x;
    if (idx >= N * 39) return;
    int n = idx / 39;
    int s = idx - n * 39;
    int row = s / 3;
    int col = s - row * 3;
    float val;
    if (row < 3) {
        if (col == 0)      val = bbde[z[n] * 3 + row];
        else if (col == 1) val = bbA[n * 3 + row];
        else               val = bbT[n * 3 + row];
    } else {
        int r = row - 3;
        if (col == 0)      val = scde[z[n] * 10 + r];
        else if (col == 1) val = scA[n * 10 + r];
        else               val = scT[n * 10 + r];
    }
    out[idx] = val;
}

extern "C" void kernel_launch(void* const* d_in, const int* in_sizes, int n_in,
                              void* d_out, int out_size, void* d_ws, size_t ws_size,
                              hipStream_t stream)
{
    const int*   cg_z        = (const int*)d_in[0];
    const float* cg_xyz      = (const float*)d_in[1];
    const int*   nbr         = (const int*)d_in[2];
    // d_in[3] = mapping (unused by reference)
    const float* S_in        = (const float*)d_in[4];
    const float* res_embed   = (const float*)d_in[5];
    const float* msg_W1      = (const float*)d_in[6];
    const float* msg_b1      = (const float*)d_in[7];
    const float* msg_W2      = (const float*)d_in[8];
    const float* msg_b2      = (const float*)d_in[9];
    const float* dist_W      = (const float*)d_in[10];
    const float* dist_b      = (const float*)d_in[11];
    const float* dense_W1    = (const float*)d_in[12];
    const float* dense_b1    = (const float*)d_in[13];
    const float* dense_W2    = (const float*)d_in[14];
    const float* dense_b2    = (const float*)d_in[15];
    const float* bb_dist_emb = (const float*)d_in[16];
    const float* sc_dist_emb = (const float*)d_in[17];
    const float* bba_W1      = (const float*)d_in[18];
    const float* bba_b1      = (const float*)d_in[19];
    const float* bba_W2      = (const float*)d_in[20];
    const float* bba_b2      = (const float*)d_in[21];
    const float* sca_W1      = (const float*)d_in[22];
    const float* sca_b1      = (const float*)d_in[23];
    const float* sca_W2      = (const float*)d_in[24];
    const float* sca_b2      = (const float*)d_in[25];
    const float* bbt_W1      = (const float*)d_in[26];
    const float* bbt_b1      = (const float*)d_in[27];
    const float* bbt_W2      = (const float*)d_in[28];
    const float* bbt_b2      = (const float*)d_in[29];
    const float* sct_W1      = (const float*)d_in[30];
    const float* sct_b1      = (const float*)d_in[31];
    const float* sct_W2      = (const float*)d_in[32];
    const float* sct_b2      = (const float*)d_in[33];
    const float* ft_W1       = (const float*)d_in[34];
    const float* ft_b1       = (const float*)d_in[35];
    const float* ft_W2       = (const float*)d_in[36];
    const float* ft_b2       = (const float*)d_in[37];

    const int N = in_sizes[0];
    const int E = in_sizes[2] / 2;

    float* ws  = (float*)d_ws;
    float* rbf = ws;  ws += (size_t)E * 16;
    float* env = ws;  ws += (size_t)E;
    float* S0  = ws;  ws += (size_t)N * 128;
    float* PHI = ws;  ws += (size_t)N * 128;
    float* V   = ws;  ws += (size_t)N * 128;
    float* scS = ws;  ws += (size_t)N * 140;
    float* bbA = ws;  ws += (size_t)N * 3;
    float* bbT = ws;  ws += (size_t)N * 3;
    float* scA = ws;  ws += (size_t)N * 10;
    float* scT = ws;  ws += (size_t)N * 10;

    edge_geom_kernel<<<DIV_UP(E, 256), 256, 0, stream>>>(nbr, cg_xyz, rbf, env, E);
    concat_s_kernel<<<DIV_UP(N * 128, 256), 256, 0, stream>>>(S_in, res_embed, cg_z, S0, N);

    for (int i = 0; i < 3; ++i) {
        mlp2_kernel<128, false, false><<<DIV_UP(N, 48), 256, 0, stream>>>(
            S0, 128, msg_W1 + (size_t)i * 128 * 128, msg_b1 + i * 128,
            msg_W2 + (size_t)i * 128 * 128, msg_b2 + i * 128, PHI, 128, N);
        (void)hipMemsetAsync(V, 0, (size_t)N * 128 * sizeof(float), stream);
        edge_msg_kernel<<<2048, 256, 0, stream>>>(
            nbr, rbf, env, PHI, dist_W + (size_t)i * 16 * 128, dist_b + i * 128, V, E);
        mlp2_kernel<128, true, true><<<DIV_UP(N, 48), 256, 0, stream>>>(
            V, 128, dense_W1 + (size_t)i * 128 * 128, dense_b1 + i * 128,
            dense_W2 + (size_t)i * 128 * 128, dense_b2 + i * 128, S0, 128, N);
    }

    head_kernel<3><<<DIV_UP(N, 4), 256, 0, stream>>>(
        S0, 128, 128, S0, 0, 0, bba_W1, bba_b1, bba_W2, bba_b2, bbA, 3, N);
    head_kernel<3><<<DIV_UP(N, 4), 256, 0, stream>>>(
        S0, 128, 128, bbA, 3, 3, bbt_W1, bbt_b1, bbt_W2, bbt_b2, bbT, 3, N);
    head_kernel<10><<<DIV_UP(N, 4), 256, 0, stream>>>(
        S0, 128, 128, S0, 0, 0, sca_W1, sca_b1, sca_W2, sca_b2, scA, 10, N);

    concat_sc_kernel<<<DIV_UP(N * 140, 256), 256, 0, stream>>>(S0, scA, scS, N);
    for (int i = 0; i < 3; ++i) {
        mlp2_kernel<138, true, true><<<DIV_UP(N, 48), 256, 0, stream>>>(
            scS, 140, sct_W1 + (size_t)i * 138 * 138, sct_b1 + i * 138,
            sct_W2 + (size_t)i * 138 * 138, sct_b2 + i * 138, scS, 140, N);
    }
    head_kernel<10><<<DIV_UP(N, 4), 256, 0, stream>>>(
        scS, 140, 138, scS, 0, 0, ft_W1, ft_b1, ft_W2, ft_b2, scT, 10, N);

    assemble_kernel<<<DIV_UP(N * 39, 256), 256, 0, stream>>>(
        cg_z, bb_dist_emb, sc_dist_emb, bbA, bbT, scA, scT, (float*)d_out, N);
}

// Round 2
// 1002.812 us; speedup vs baseline: 1.4040x; 1.4040x over previous
//
#include <hip/hip_runtime.h>
#include <hip/hip_bf16.h>

#define DIV_UP(a,b) (((a)+(b)-1)/(b))

__device__ __forceinline__ float silu_f(float x) {
    return x / (1.0f + __expf(-x));
}

// ---------------------------------------------------------------------------
// Edge geometry: dist -> rbf[E][16], env[E].  sin(n x) via Chebyshev recurrence.
// ---------------------------------------------------------------------------
__global__ __launch_bounds__(256) void edge_geom_kernel(
    const int* __restrict__ nbr, const float* __restrict__ xyz,
    float* __restrict__ rbf, float* __restrict__ env, int E)
{
    int e = blockIdx.x * 256 + threadIdx.x;
    if (e >= E) return;
    int i = nbr[2 * e], j = nbr[2 * e + 1];
    float dx = xyz[3 * j + 0] - xyz[3 * i + 0];
    float dy = xyz[3 * j + 1] - xyz[3 * i + 1];
    float dz = xyz[3 * j + 2] - xyz[3 * i + 2];
    float dist = sqrtf(dx * dx + dy * dy + dz * dz);
    float x = dist * 0.3141592653589793f;   // pi/CUTOFF
    float s, c;
    __sincosf(x, &s, &c);
    float inv = 1.0f / dist;
    float two_c = 2.0f * c;
    float sm1 = 0.0f, s0 = s;
    float out[16];
    #pragma unroll
    for (int k = 0; k < 16; ++k) {
        out[k] = s0 * inv;
        float s1 = two_c * s0 - sm1;
        sm1 = s0; s0 = s1;
    }
    float4* rp = (float4*)(rbf + (size_t)e * 16);
    rp[0] = make_float4(out[0],  out[1],  out[2],  out[3]);
    rp[1] = make_float4(out[4],  out[5],  out[6],  out[7]);
    rp[2] = make_float4(out[8],  out[9],  out[10], out[11]);
    rp[3] = make_float4(out[12], out[13], out[14], out[15]);
    env[e] = (dist < 10.0f) ? 0.5f * (c + 1.0f) : 0.0f;
}

// ---------------------------------------------------------------------------
// CSR build: histogram -> single-block scan -> cursor scatter
// ---------------------------------------------------------------------------
__global__ __launch_bounds__(256) void hist_kernel(
    const int* __restrict__ nbr, int* __restrict__ counts, int E)
{
    int e = blockIdx.x * 256 + threadIdx.x;
    if (e < E) atomicAdd(&counts[nbr[2 * e]], 1);
}

__global__ __launch_bounds__(1024) void scan_kernel(
    const int* __restrict__ counts, int* __restrict__ eptr, int N)
{
    __shared__ int part[1024];
    const int t = threadIdx.x;
    const int chunk = DIV_UP(N, 1024);
    int s = 0;
    for (int c = 0; c < chunk; ++c) {
        int idx = t * chunk + c;
        if (idx < N) s += counts[idx];
    }
    part[t] = s;
    __syncthreads();
    for (int off = 1; off < 1024; off <<= 1) {
        int v = (t >= off) ? part[t - off] : 0;
        __syncthreads();
        part[t] += v;
        __syncthreads();
    }
    int pre = (t > 0) ? part[t - 1] : 0;
    for (int c = 0; c < chunk; ++c) {
        int idx = t * chunk + c;
        if (idx < N) { eptr[idx] = pre; pre += counts[idx]; }
    }
    if (t == 1023) eptr[N] = part[1023];
}

__global__ __launch_bounds__(256) void scatter_kernel(
    const int* __restrict__ nbr, const int* __restrict__ eptr,
    int* __restrict__ cursor, int* __restrict__ eids, int E)
{
    int e = blockIdx.x * 256 + threadIdx.x;
    if (e >= E) return;
    int i = nbr[2 * e];
    int pos = atomicAdd(&cursor[i], 1);
    eids[eptr[i] + pos] = e;
}

// ---------------------------------------------------------------------------
// S0 = concat(S[N,124], res_embed[cg_z][N,4])  -> [N,128]
// ---------------------------------------------------------------------------
__global__ __launch_bounds__(256) void concat_s_kernel(
    const float* __restrict__ S, const float* __restrict__ res_embed,
    const int* __restrict__ z, float* __restrict__ S0, int N)
{
    int idx = blockIdx.x * 256 + threadIdx.x;
    if (idx >= N * 128) return;
    int n = idx >> 7, c = idx & 127;
    float val = (c < 124) ? S[n * 124 + c] : res_embed[z[n] * 4 + (c - 124)];
    S0[idx] = val;
}

// ---------------------------------------------------------------------------
// scS = concat(S0[N,128], scA[N,10]) -> [N,140] (2 pad zeros)
// ---------------------------------------------------------------------------
__global__ __launch_bounds__(256) void concat_sc_kernel(
    const float* __restrict__ S0, const float* __restrict__ scA,
    float* __restrict__ scS, int N)
{
    int idx = blockIdx.x * 256 + threadIdx.x;
    if (idx >= N * 140) return;
    int n = idx / 140, c = idx - n * 140;
    float val = 0.0f;
    if (c < 128)       val = S0[n * 128 + c];
    else if (c < 138)  val = scA[n * 10 + (c - 128)];
    scS[idx] = val;
}

// ---------------------------------------------------------------------------
// Generic two-stage MLP over rows. OutT = float or __hip_bfloat16.
// ---------------------------------------------------------------------------
template<int K, bool PREACT, bool RESID, typename OutT>
__global__ __launch_bounds__(256) void mlp2_kernel(
    const float* __restrict__ X, int ldX,
    const float* __restrict__ W1, const float* __restrict__ b1,
    const float* __restrict__ W2, const float* __restrict__ b2,
    OutT* __restrict__ Y, int ldY, int nrows)
{
    constexpr int NC = (K + 31) / 32;   // 4 (K=128) or 5 (K=138)
    constexpr int ROWS = 48;
    constexpr int RR = 6;
    __shared__ float Xs[ROWS * K];
    __shared__ float Hs[ROWS * K];
    const int tid = threadIdx.x;
    const int row0 = blockIdx.x * ROWS;

    for (int idx = tid; idx < ROWS * K; idx += 256) {
        int r = idx / K, c = idx - r * K;
        int gr = row0 + r;
        float x = (gr < nrows) ? X[(size_t)gr * ldX + c] : 0.0f;
        if (PREACT) x = silu_f(x);
        Xs[idx] = x;
    }
    __syncthreads();

    const int cc = tid & 31;
    const int r0 = (tid >> 5) * RR;

    float acc[NC][RR];
    #pragma unroll
    for (int jc = 0; jc < NC; ++jc) {
        int col = cc + 32 * jc;
        float bv = (col < K) ? b1[col] : 0.0f;
        #pragma unroll
        for (int rr = 0; rr < RR; ++rr) acc[jc][rr] = bv;
    }
    for (int k = 0; k < K; ++k) {
        float w[NC];
        #pragma unroll
        for (int jc = 0; jc < NC; ++jc) {
            int col = cc + 32 * jc;
            w[jc] = (col < K) ? W1[k * K + col] : 0.0f;
        }
        float xv[RR];
        #pragma unroll
        for (int rr = 0; rr < RR; ++rr) xv[rr] = Xs[(r0 + rr) * K + k];
        #pragma unroll
        for (int jc = 0; jc < NC; ++jc)
            #pragma unroll
            for (int rr = 0; rr < RR; ++rr)
                acc[jc][rr] = fmaf(xv[rr], w[jc], acc[jc][rr]);
    }
    #pragma unroll
    for (int jc = 0; jc < NC; ++jc) {
        int col = cc + 32 * jc;
        if (col < K) {
            #pragma unroll
            for (int rr = 0; rr < RR; ++rr)
                Hs[(r0 + rr) * K + col] = silu_f(acc[jc][rr]);
        }
    }
    __syncthreads();

    #pragma unroll
    for (int jc = 0; jc < NC; ++jc) {
        int col = cc + 32 * jc;
        float bv = (col < K) ? b2[col] : 0.0f;
        #pragma unroll
        for (int rr = 0; rr < RR; ++rr) acc[jc][rr] = bv;
    }
    for (int k = 0; k < K; ++k) {
        float w[NC];
        #pragma unroll
        for (int jc = 0; jc < NC; ++jc) {
            int col = cc + 32 * jc;
            w[jc] = (col < K) ? W2[k * K + col] : 0.0f;
        }
        float xv[RR];
        #pragma unroll
        for (int rr = 0; rr < RR; ++rr) xv[rr] = Hs[(r0 + rr) * K + k];
        #pragma unroll
        for (int jc = 0; jc < NC; ++jc)
            #pragma unroll
            for (int rr = 0; rr < RR; ++rr)
                acc[jc][rr] = fmaf(xv[rr], w[jc], acc[jc][rr]);
    }
    #pragma unroll
    for (int jc = 0; jc < NC; ++jc) {
        int col = cc + 32 * jc;
        if (col < K) {
            #pragma unroll
            for (int rr = 0; rr < RR; ++rr) {
                int gr = row0 + r0 + rr;
                if (gr < nrows) {
                    size_t off = (size_t)gr * ldY + col;
                    float val = acc[jc][rr];
                    if (RESID) val += (float)Y[off];
                    if constexpr (sizeof(OutT) == 2)
                        Y[off] = __float2bfloat16(val);
                    else
                        Y[off] = val;
                }
            }
        }
    }
}

// ---------------------------------------------------------------------------
// Gathered edge message + segment sum, CSR form. One wave (64 lanes) per node;
// lane owns cols (2*lane, 2*lane+1); dist_W columns held in registers.
//   v[i][c] = sum_{e in CSR[i]} phi_bf16[j_e][c] * ((rbf[e] @ distW + db)[c] * env[e])
// ---------------------------------------------------------------------------
__global__ __launch_bounds__(256) void gather_msg_kernel(
    const int* __restrict__ eids, const int* __restrict__ eptr,
    const int* __restrict__ nbr,
    const float* __restrict__ rbf, const float* __restrict__ env,
    const __hip_bfloat16* __restrict__ phi,
    const float* __restrict__ distW, const float* __restrict__ distb,
    float* __restrict__ v, int N)
{
    const int wid = threadIdx.x >> 6;
    const int lane = threadIdx.x & 63;
    const int n = blockIdx.x * 4 + wid;
    if (n >= N) return;

    const int c0 = 2 * lane;
    float dw0[16], dw1[16];
    #pragma unroll
    for (int k = 0; k < 16; ++k) {
        dw0[k] = distW[k * 128 + c0];
        dw1[k] = distW[k * 128 + c0 + 1];
    }
    const float db0 = distb[c0];
    const float db1 = distb[c0 + 1];

    float acc0 = 0.0f, acc1 = 0.0f;
    const int p0 = eptr[n], p1 = eptr[n + 1];
    for (int p = p0; p < p1; ++p) {
        const int e = eids[p];
        const int j = nbr[2 * e + 1];
        const float ev = env[e];
        const float4* rp = (const float4*)(rbf + (size_t)e * 16);
        float4 r0 = rp[0], r1 = rp[1], r2 = rp[2], r3 = rp[3];
        // load phi early to overlap with the dot product
        __hip_bfloat162 ph = *(const __hip_bfloat162*)(phi + (size_t)j * 128 + c0);
        float w0 = db0, w1 = db1;
        w0 = fmaf(r0.x, dw0[0], w0);  w1 = fmaf(r0.x, dw1[0], w1);
        w0 = fmaf(r0.y, dw0[1], w0);  w1 = fmaf(r0.y, dw1[1], w1);
        w0 = fmaf(r0.z, dw0[2], w0);  w1 = fmaf(r0.z, dw1[2], w1);
        w0 = fmaf(r0.w, dw0[3], w0);  w1 = fmaf(r0.w, dw1[3], w1);
        w0 = fmaf(r1.x, dw0[4], w0);  w1 = fmaf(r1.x, dw1[4], w1);
        w0 = fmaf(r1.y, dw0[5], w0);  w1 = fmaf(r1.y, dw1[5], w1);
        w0 = fmaf(r1.z, dw0[6], w0);  w1 = fmaf(r1.z, dw1[6], w1);
        w0 = fmaf(r1.w, dw0[7], w0);  w1 = fmaf(r1.w, dw1[7], w1);
        w0 = fmaf(r2.x, dw0[8], w0);  w1 = fmaf(r2.x, dw1[8], w1);
        w0 = fmaf(r2.y, dw0[9], w0);  w1 = fmaf(r2.y, dw1[9], w1);
        w0 = fmaf(r2.z, dw0[10], w0); w1 = fmaf(r2.z, dw1[10], w1);
        w0 = fmaf(r2.w, dw0[11], w0); w1 = fmaf(r2.w, dw1[11], w1);
        w0 = fmaf(r3.x, dw0[12], w0); w1 = fmaf(r3.x, dw1[12], w1);
        w0 = fmaf(r3.y, dw0[13], w0); w1 = fmaf(r3.y, dw1[13], w1);
        w0 = fmaf(r3.z, dw0[14], w0); w1 = fmaf(r3.z, dw1[14], w1);
        w0 = fmaf(r3.w, dw0[15], w0); w1 = fmaf(r3.w, dw1[15], w1);
        acc0 = fmaf(w0 * ev, __bfloat162float(ph.x), acc0);
        acc1 = fmaf(w1 * ev, __bfloat162float(ph.y), acc1);
    }
    float2* vp = (float2*)(v + (size_t)n * 128 + c0);
    *vp = make_float2(acc0, acc1);
}

// ---------------------------------------------------------------------------
// Small head: out = silu( silu(x) @ W1 + b1 ) @ W2 + b2   (final linear, no act)
// ---------------------------------------------------------------------------
template<int M>
__global__ __launch_bounds__(256) void head_kernel(
    const float* __restrict__ X, int ldX, int K1,
    const float* __restrict__ X2, int ldX2, int K2,
    const float* __restrict__ W1, const float* __restrict__ b1,
    const float* __restrict__ W2, const float* __restrict__ b2,
    float* __restrict__ out, int ldOut, int nrows)
{
    const int wid = threadIdx.x >> 6;
    const int lane = threadIdx.x & 63;
    const int n = blockIdx.x * 4 + wid;
    if (n >= nrows) return;
    const int K = K1 + K2;
    float sx[3];
    #pragma unroll
    for (int t = 0; t < 3; ++t) {
        int k = lane + 64 * t;
        float v = 0.0f;
        if (k < K1) v = X[(size_t)n * ldX + k];
        else if (k < K) v = X2[(size_t)n * ldX2 + (k - K1)];
        sx[t] = (k < K) ? silu_f(v) : 0.0f;
    }
    float acc[M];
    #pragma unroll
    for (int m = 0; m < M; ++m) {
        float a = 0.0f;
        #pragma unroll
        for (int t = 0; t < 3; ++t) {
            int k = lane + 64 * t;
            if (k < K) a = fmaf(sx[t], W1[k * M + m], a);
        }
        acc[m] = a;
    }
    #pragma unroll
    for (int m = 0; m < M; ++m) {
        #pragma unroll
        for (int off = 32; off > 0; off >>= 1)
            acc[m] += __shfl_xor(acc[m], off, 64);
    }
    float tm[M];
    #pragma unroll
    for (int m = 0; m < M; ++m) tm[m] = silu_f(acc[m] + b1[m]);
    if (lane < M) {
        float o = b2[lane];
        #pragma unroll
        for (int m = 0; m < M; ++m) o = fmaf(tm[m], W2[m * M + lane], o);
        out[(size_t)n * ldOut + lane] = o;
    }
}

// ---------------------------------------------------------------------------
// Output assembly: out[N][13][3]
// ---------------------------------------------------------------------------
__global__ __launch_bounds__(256) void assemble_kernel(
    const int* __restrict__ z,
    const float* __restrict__ bbde, const float* __restrict__ scde,
    const float* __restrict__ bbA, const float* __restrict__ bbT,
    const float* __restrict__ scA, const float* __restrict__ scT,
    float* __restrict__ out, int N)
{
    int idx = blockIdx.x * 256 + threadIdx.x;
    if (idx >= N * 39) return;
    int n = idx / 39;
    int s = idx - n * 39;
    int row = s / 3;
    int col = s - row * 3;
    float val;
    if (row < 3) {
        if (col == 0)      val = bbde[z[n] * 3 + row];
        else if (col == 1) val = bbA[n * 3 + row];
        else               val = bbT[n * 3 + row];
    } else {
        int r = row - 3;
        if (col == 0)      val = scde[z[n] * 10 + r];
        else if (col == 1) val = scA[n * 10 + r];
        else               val = scT[n * 10 + r];
    }
    out[idx] = val;
}

extern "C" void kernel_launch(void* const* d_in, const int* in_sizes, int n_in,
                              void* d_out, int out_size, void* d_ws, size_t ws_size,
                              hipStream_t stream)
{
    const int*   cg_z        = (const int*)d_in[0];
    const float* cg_xyz      = (const float*)d_in[1];
    const int*   nbr         = (const int*)d_in[2];
    // d_in[3] = mapping (unused by reference)
    const float* S_in        = (const float*)d_in[4];
    const float* res_embed   = (const float*)d_in[5];
    const float* msg_W1      = (const float*)d_in[6];
    const float* msg_b1      = (const float*)d_in[7];
    const float* msg_W2      = (const float*)d_in[8];
    const float* msg_b2      = (const float*)d_in[9];
    const float* dist_W      = (const float*)d_in[10];
    const float* dist_b      = (const float*)d_in[11];
    const float* dense_W1    = (const float*)d_in[12];
    const float* dense_b1    = (const float*)d_in[13];
    const float* dense_W2    = (const float*)d_in[14];
    const float* dense_b2    = (const float*)d_in[15];
    const float* bb_dist_emb = (const float*)d_in[16];
    const float* sc_dist_emb = (const float*)d_in[17];
    const float* bba_W1      = (const float*)d_in[18];
    const float* bba_b1      = (const float*)d_in[19];
    const float* bba_W2      = (const float*)d_in[20];
    const float* bba_b2      = (const float*)d_in[21];
    const float* sca_W1      = (const float*)d_in[22];
    const float* sca_b1      = (const float*)d_in[23];
    const float* sca_W2      = (const float*)d_in[24];
    const float* sca_b2      = (const float*)d_in[25];
    const float* bbt_W1      = (const float*)d_in[26];
    const float* bbt_b1      = (const float*)d_in[27];
    const float* bbt_W2      = (const float*)d_in[28];
    const float* bbt_b2      = (const float*)d_in[29];
    const float* sct_W1      = (const float*)d_in[30];
    const float* sct_b1      = (const float*)d_in[31];
    const float* sct_W2      = (const float*)d_in[32];
    const float* sct_b2      = (const float*)d_in[33];
    const float* ft_W1       = (const float*)d_in[34];
    const float* ft_b1       = (const float*)d_in[35];
    const float* ft_W2       = (const float*)d_in[36];
    const float* ft_b2       = (const float*)d_in[37];

    const int N = in_sizes[0];
    const int E = in_sizes[2] / 2;

    float* ws  = (float*)d_ws;
    float* rbf = ws;  ws += (size_t)E * 16;
    float* env = ws;  ws += (size_t)E;
    float* S0  = ws;  ws += (size_t)N * 128;
    float* V   = ws;  ws += (size_t)N * 128;
    float* scS = ws;  ws += (size_t)N * 140;
    float* bbA = ws;  ws += (size_t)N * 3;
    float* bbT = ws;  ws += (size_t)N * 3;
    float* scA = ws;  ws += (size_t)N * 10;
    float* scT = ws;  ws += (size_t)N * 10;
    __hip_bfloat16* PHI = (__hip_bfloat16*)ws;  ws += (size_t)N * 64;  // N*128 bf16
    int* eids   = (int*)ws;  ws = (float*)((int*)ws + E);
    int* eptr   = (int*)ws;  ws = (float*)((int*)ws + (N + 1));
    int* counts = (int*)ws;  ws = (float*)((int*)ws + N);
    int* cursor = (int*)ws;  ws = (float*)((int*)ws + N);

    // CSR build (counts and cursor are adjacent -> one memset)
    (void)hipMemsetAsync(counts, 0, (size_t)2 * N * sizeof(int), stream);
    hist_kernel<<<DIV_UP(E, 256), 256, 0, stream>>>(nbr, counts, E);
    scan_kernel<<<1, 1024, 0, stream>>>(counts, eptr, N);
    scatter_kernel<<<DIV_UP(E, 256), 256, 0, stream>>>(nbr, eptr, cursor, eids, E);

    edge_geom_kernel<<<DIV_UP(E, 256), 256, 0, stream>>>(nbr, cg_xyz, rbf, env, E);
    concat_s_kernel<<<DIV_UP(N * 128, 256), 256, 0, stream>>>(S_in, res_embed, cg_z, S0, N);

    for (int i = 0; i < 3; ++i) {
        mlp2_kernel<128, false, false, __hip_bfloat16><<<DIV_UP(N, 48), 256, 0, stream>>>(
            S0, 128, msg_W1 + (size_t)i * 128 * 128, msg_b1 + i * 128,
            msg_W2 + (size_t)i * 128 * 128, msg_b2 + i * 128, PHI, 128, N);
        gather_msg_kernel<<<DIV_UP(N, 4), 256, 0, stream>>>(
            eids, eptr, nbr, rbf, env, PHI,
            dist_W + (size_t)i * 16 * 128, dist_b + i * 128, V, N);
        mlp2_kernel<128, true, true, float><<<DIV_UP(N, 48), 256, 0, stream>>>(
            V, 128, dense_W1 + (size_t)i * 128 * 128, dense_b1 + i * 128,
            dense_W2 + (size_t)i * 128 * 128, dense_b2 + i * 128, S0, 128, N);
    }

    head_kernel<3><<<DIV_UP(N, 4), 256, 0, stream>>>(
        S0, 128, 128, S0, 0, 0, bba_W1, bba_b1, bba_W2, bba_b2, bbA, 3, N);
    head_kernel<3><<<DIV_UP(N, 4), 256, 0, stream>>>(
        S0, 128, 128, bbA, 3, 3, bbt_W1, bbt_b1, bbt_W2, bbt_b2, bbT, 3, N);
    head_kernel<10><<<DIV_UP(N, 4), 256, 0, stream>>>(
        S0, 128, 128, S0, 0, 0, sca_W1, sca_b1, sca_W2, sca_b2, scA, 10, N);

    concat_sc_kernel<<<DIV_UP(N * 140, 256), 256, 0, stream>>>(S0, scA, scS, N);
    for (int i = 0; i < 3; ++i) {
        mlp2_kernel<138, true, true, float><<<DIV_UP(N, 48), 256, 0, stream>>>(
            scS, 140, sct_W1 + (size_t)i * 138 * 138, sct_b1 + i * 138,
            sct_W2 + (size_t)i * 138 * 138, sct_b2 + i * 138, scS, 140, N);
    }
    head_kernel<10><<<DIV_UP(N, 4), 256, 0, stream>>>(
        scS, 140, 138, scS, 0, 0, ft_W1, ft_b1, ft_W2, ft_b2, scT, 10, N);

    assemble_kernel<<<DIV_UP(N * 39, 256), 256, 0, stream>>>(
        cg_z, bb_dist_emb, sc_dist_emb, bbA, bbT, scA, scT, (float*)d_out, N);
}

// Round 3
// 961.696 us; speedup vs baseline: 1.4640x; 1.0428x over previous
//
#include <hip/hip_runtime.h>
#include <hip/hip_bf16.h>

#define DIV_UP(a,b) (((a)+(b)-1)/(b))

__device__ __forceinline__ float silu_f(float x) {
    return x / (1.0f + __expf(-x));
}

// ---------------------------------------------------------------------------
// CSR build: histogram -> single-block scan
// ---------------------------------------------------------------------------
__global__ __launch_bounds__(256) void hist_kernel(
    const int* __restrict__ nbr, int* __restrict__ counts, int E)
{
    int e = blockIdx.x * 256 + threadIdx.x;
    if (e < E) atomicAdd(&counts[nbr[2 * e]], 1);
}

__global__ __launch_bounds__(1024) void scan_kernel(
    const int* __restrict__ counts, int* __restrict__ eptr, int N)
{
    __shared__ int part[1024];
    const int t = threadIdx.x;
    const int chunk = DIV_UP(N, 1024);
    int s = 0;
    for (int c = 0; c < chunk; ++c) {
        int idx = t * chunk + c;
        if (idx < N) s += counts[idx];
    }
    part[t] = s;
    __syncthreads();
    for (int off = 1; off < 1024; off <<= 1) {
        int v = (t >= off) ? part[t - off] : 0;
        __syncthreads();
        part[t] += v;
        __syncthreads();
    }
    int pre = (t > 0) ? part[t - 1] : 0;
    for (int c = 0; c < chunk; ++c) {
        int idx = t * chunk + c;
        if (idx < N) { eptr[idx] = pre; pre += counts[idx]; }
    }
    if (t == 1023) eptr[N] = part[1023];
}

// ---------------------------------------------------------------------------
// Fused edge geometry + CSR scatter. Writes edge records in CSR (sorted-by-i)
// order so the per-node gather streams them linearly:
//   rbfs[p][16] = sin(n*d*pi/10)/d * env   (premultiplied by envelope)
//   envs[p]     = env                       (for the bias term)
//   js[p]       = source node j
// ---------------------------------------------------------------------------
__global__ __launch_bounds__(256) void geom_scatter_kernel(
    const int* __restrict__ nbr, const float* __restrict__ xyz,
    const int* __restrict__ eptr, int* __restrict__ cursor,
    float* __restrict__ rbfs, float* __restrict__ envs, int* __restrict__ js,
    int E)
{
    int e = blockIdx.x * 256 + threadIdx.x;
    if (e >= E) return;
    int i = nbr[2 * e], j = nbr[2 * e + 1];
    float dx = xyz[3 * j + 0] - xyz[3 * i + 0];
    float dy = xyz[3 * j + 1] - xyz[3 * i + 1];
    float dz = xyz[3 * j + 2] - xyz[3 * i + 2];
    float dist = sqrtf(dx * dx + dy * dy + dz * dz);
    float x = dist * 0.3141592653589793f;   // pi/CUTOFF
    float s, c;
    __sincosf(x, &s, &c);
    float env = (dist < 10.0f) ? 0.5f * (c + 1.0f) : 0.0f;
    float inv_env = env / dist;
    float two_c = 2.0f * c;
    float sm1 = 0.0f, s0 = s;
    float out[16];
    #pragma unroll
    for (int k = 0; k < 16; ++k) {
        out[k] = s0 * inv_env;
        float s1 = two_c * s0 - sm1;
        sm1 = s0; s0 = s1;
    }
    int p = eptr[i] + atomicAdd(&cursor[i], 1);
    float4* rp = (float4*)(rbfs + (size_t)p * 16);
    rp[0] = make_float4(out[0],  out[1],  out[2],  out[3]);
    rp[1] = make_float4(out[4],  out[5],  out[6],  out[7]);
    rp[2] = make_float4(out[8],  out[9],  out[10], out[11]);
    rp[3] = make_float4(out[12], out[13], out[14], out[15]);
    envs[p] = env;
    js[p] = j;
}

// ---------------------------------------------------------------------------
// S0 = concat(S[N,124], res_embed[cg_z][N,4])  -> [N,128]
// ---------------------------------------------------------------------------
__global__ __launch_bounds__(256) void concat_s_kernel(
    const float* __restrict__ S, const float* __restrict__ res_embed,
    const int* __restrict__ z, float* __restrict__ S0, int N)
{
    int idx = blockIdx.x * 256 + threadIdx.x;
    if (idx >= N * 128) return;
    int n = idx >> 7, c = idx & 127;
    float val = (c < 124) ? S[n * 124 + c] : res_embed[z[n] * 4 + (c - 124)];
    S0[idx] = val;
}

// ---------------------------------------------------------------------------
// scS = concat(S0[N,128], scA[N,10]) -> [N,140] (2 pad zeros)
// ---------------------------------------------------------------------------
__global__ __launch_bounds__(256) void concat_sc_kernel(
    const float* __restrict__ S0, const float* __restrict__ scA,
    float* __restrict__ scS, int N)
{
    int idx = blockIdx.x * 256 + threadIdx.x;
    if (idx >= N * 140) return;
    int n = idx / 140, c = idx - n * 140;
    float val = 0.0f;
    if (c < 128)       val = S0[n * 128 + c];
    else if (c < 138)  val = scA[n * 10 + (c - 128)];
    scS[idx] = val;
}

// ---------------------------------------------------------------------------
// Generic two-stage MLP over rows. OutT = float or __hip_bfloat16.
// ---------------------------------------------------------------------------
template<int K, bool PREACT, bool RESID, typename OutT>
__global__ __launch_bounds__(256) void mlp2_kernel(
    const float* __restrict__ X, int ldX,
    const float* __restrict__ W1, const float* __restrict__ b1,
    const float* __restrict__ W2, const float* __restrict__ b2,
    OutT* __restrict__ Y, int ldY, int nrows)
{
    constexpr int NC = (K + 31) / 32;   // 4 (K=128) or 5 (K=138)
    constexpr int ROWS = 48;
    constexpr int RR = 6;
    __shared__ float Xs[ROWS * K];
    __shared__ float Hs[ROWS * K];
    const int tid = threadIdx.x;
    const int row0 = blockIdx.x * ROWS;

    for (int idx = tid; idx < ROWS * K; idx += 256) {
        int r = idx / K, c = idx - r * K;
        int gr = row0 + r;
        float x = (gr < nrows) ? X[(size_t)gr * ldX + c] : 0.0f;
        if (PREACT) x = silu_f(x);
        Xs[idx] = x;
    }
    __syncthreads();

    const int cc = tid & 31;
    const int r0 = (tid >> 5) * RR;

    float acc[NC][RR];
    #pragma unroll
    for (int jc = 0; jc < NC; ++jc) {
        int col = cc + 32 * jc;
        float bv = (col < K) ? b1[col] : 0.0f;
        #pragma unroll
        for (int rr = 0; rr < RR; ++rr) acc[jc][rr] = bv;
    }
    for (int k = 0; k < K; ++k) {
        float w[NC];
        #pragma unroll
        for (int jc = 0; jc < NC; ++jc) {
            int col = cc + 32 * jc;
            w[jc] = (col < K) ? W1[k * K + col] : 0.0f;
        }
        float xv[RR];
        #pragma unroll
        for (int rr = 0; rr < RR; ++rr) xv[rr] = Xs[(r0 + rr) * K + k];
        #pragma unroll
        for (int jc = 0; jc < NC; ++jc)
            #pragma unroll
            for (int rr = 0; rr < RR; ++rr)
                acc[jc][rr] = fmaf(xv[rr], w[jc], acc[jc][rr]);
    }
    #pragma unroll
    for (int jc = 0; jc < NC; ++jc) {
        int col = cc + 32 * jc;
        if (col < K) {
            #pragma unroll
            for (int rr = 0; rr < RR; ++rr)
                Hs[(r0 + rr) * K + col] = silu_f(acc[jc][rr]);
        }
    }
    __syncthreads();

    #pragma unroll
    for (int jc = 0; jc < NC; ++jc) {
        int col = cc + 32 * jc;
        float bv = (col < K) ? b2[col] : 0.0f;
        #pragma unroll
        for (int rr = 0; rr < RR; ++rr) acc[jc][rr] = bv;
    }
    for (int k = 0; k < K; ++k) {
        float w[NC];
        #pragma unroll
        for (int jc = 0; jc < NC; ++jc) {
            int col = cc + 32 * jc;
            w[jc] = (col < K) ? W2[k * K + col] : 0.0f;
        }
        float xv[RR];
        #pragma unroll
        for (int rr = 0; rr < RR; ++rr) xv[rr] = Hs[(r0 + rr) * K + k];
        #pragma unroll
        for (int jc = 0; jc < NC; ++jc)
            #pragma unroll
            for (int rr = 0; rr < RR; ++rr)
                acc[jc][rr] = fmaf(xv[rr], w[jc], acc[jc][rr]);
    }
    #pragma unroll
    for (int jc = 0; jc < NC; ++jc) {
        int col = cc + 32 * jc;
        if (col < K) {
            #pragma unroll
            for (int rr = 0; rr < RR; ++rr) {
                int gr = row0 + r0 + rr;
                if (gr < nrows) {
                    size_t off = (size_t)gr * ldY + col;
                    float val = acc[jc][rr];
                    if (RESID) val += (float)Y[off];
                    if constexpr (sizeof(OutT) == 2)
                        Y[off] = __float2bfloat16(val);
                    else
                        Y[off] = val;
                }
            }
        }
    }
}

// ---------------------------------------------------------------------------
// Gathered edge message + segment sum over CSR-sorted streaming edge records.
// One wave per node; lane owns cols (2*lane, 2*lane+1). Unrolled x2 so two
// edges' load chains (j -> phi row) are in flight.
//   v[n][c] = sum_p  (rbfs[p]@distW[:,c] + db[c]*envs[p]) * phi[js[p]][c]
// ---------------------------------------------------------------------------
__global__ __launch_bounds__(256) void gather_msg_kernel(
    const int* __restrict__ eptr,
    const float* __restrict__ rbfs, const float* __restrict__ envs,
    const int* __restrict__ js,
    const __hip_bfloat16* __restrict__ phi,
    const float* __restrict__ distW, const float* __restrict__ distb,
    float* __restrict__ v, int N)
{
    const int wid = threadIdx.x >> 6;
    const int lane = threadIdx.x & 63;
    const int n = blockIdx.x * 4 + wid;
    if (n >= N) return;

    const int c0 = 2 * lane;
    float dw0[16], dw1[16];
    #pragma unroll
    for (int k = 0; k < 16; ++k) {
        dw0[k] = distW[k * 128 + c0];
        dw1[k] = distW[k * 128 + c0 + 1];
    }
    const float db0 = distb[c0];
    const float db1 = distb[c0 + 1];
    const __hip_bfloat162* __restrict__ phi2 = (const __hip_bfloat162*)phi;

    float acc0 = 0.0f, acc1 = 0.0f;
    const int p0 = eptr[n], p1 = eptr[n + 1];
    int p = p0;

    #define EDGE_BODY(PIDX)                                                    \
        {                                                                      \
            const int jj = js[PIDX];                                           \
            const float ev = envs[PIDX];                                       \
            const float4* rp = (const float4*)(rbfs + (size_t)(PIDX) * 16);    \
            float4 r0 = rp[0], r1 = rp[1], r2 = rp[2], r3 = rp[3];             \
            __hip_bfloat162 ph = phi2[(size_t)jj * 64 + lane];                 \
            float w0 = db0 * ev, w1 = db1 * ev;                                \
            w0 = fmaf(r0.x, dw0[0], w0);  w1 = fmaf(r0.x, dw1[0], w1);         \
            w0 = fmaf(r0.y, dw0[1], w0);  w1 = fmaf(r0.y, dw1[1], w1);         \
            w0 = fmaf(r0.z, dw0[2], w0);  w1 = fmaf(r0.z, dw1[2], w1);         \
            w0 = fmaf(r0.w, dw0[3], w0);  w1 = fmaf(r0.w, dw1[3], w1);         \
            w0 = fmaf(r1.x, dw0[4], w0);  w1 = fmaf(r1.x, dw1[4], w1);         \
            w0 = fmaf(r1.y, dw0[5], w0);  w1 = fmaf(r1.y, dw1[5], w1);         \
            w0 = fmaf(r1.z, dw0[6], w0);  w1 = fmaf(r1.z, dw1[6], w1);         \
            w0 = fmaf(r1.w, dw0[7], w0);  w1 = fmaf(r1.w, dw1[7], w1);         \
            w0 = fmaf(r2.x, dw0[8], w0);  w1 = fmaf(r2.x, dw1[8], w1);         \
            w0 = fmaf(r2.y, dw0[9], w0);  w1 = fmaf(r2.y, dw1[9], w1);         \
            w0 = fmaf(r2.z, dw0[10], w0); w1 = fmaf(r2.z, dw1[10], w1);        \
            w0 = fmaf(r2.w, dw0[11], w0); w1 = fmaf(r2.w, dw1[11], w1);        \
            w0 = fmaf(r3.x, dw0[12], w0); w1 = fmaf(r3.x, dw1[12], w1);        \
            w0 = fmaf(r3.y, dw0[13], w0); w1 = fmaf(r3.y, dw1[13], w1);        \
            w0 = fmaf(r3.z, dw0[14], w0); w1 = fmaf(r3.z, dw1[14], w1);        \
            w0 = fmaf(r3.w, dw0[15], w0); w1 = fmaf(r3.w, dw1[15], w1);        \
            acc0 = fmaf(w0, __bfloat162float(ph.x), acc0);                     \
            acc1 = fmaf(w1, __bfloat162float(ph.y), acc1);                     \
        }

    for (; p + 2 <= p1; p += 2) {
        EDGE_BODY(p)
        EDGE_BODY(p + 1)
    }
    if (p < p1) EDGE_BODY(p)
    #undef EDGE_BODY

    float2* vp = (float2*)(v + (size_t)n * 128 + c0);
    *vp = make_float2(acc0, acc1);
}

// ---------------------------------------------------------------------------
// Small head: out = silu( silu(x) @ W1 + b1 ) @ W2 + b2   (final linear, no act)
// ---------------------------------------------------------------------------
template<int M>
__global__ __launch_bounds__(256) void head_kernel(
    const float* __restrict__ X, int ldX, int K1,
    const float* __restrict__ X2, int ldX2, int K2,
    const float* __restrict__ W1, const float* __restrict__ b1,
    const float* __restrict__ W2, const float* __restrict__ b2,
    float* __restrict__ out, int ldOut, int nrows)
{
    const int wid = threadIdx.x >> 6;
    const int lane = threadIdx.x & 63;
    const int n = blockIdx.x * 4 + wid;
    if (n >= nrows) return;
    const int K = K1 + K2;
    float sx[3];
    #pragma unroll
    for (int t = 0; t < 3; ++t) {
        int k = lane + 64 * t;
        float v = 0.0f;
        if (k < K1) v = X[(size_t)n * ldX + k];
        else if (k < K) v = X2[(size_t)n * ldX2 + (k - K1)];
        sx[t] = (k < K) ? silu_f(v) : 0.0f;
    }
    float acc[M];
    #pragma unroll
    for (int m = 0; m < M; ++m) {
        float a = 0.0f;
        #pragma unroll
        for (int t = 0; t < 3; ++t) {
            int k = lane + 64 * t;
            if (k < K) a = fmaf(sx[t], W1[k * M + m], a);
        }
        acc[m] = a;
    }
    #pragma unroll
    for (int m = 0; m < M; ++m) {
        #pragma unroll
        for (int off = 32; off > 0; off >>= 1)
            acc[m] += __shfl_xor(acc[m], off, 64);
    }
    float tm[M];
    #pragma unroll
    for (int m = 0; m < M; ++m) tm[m] = silu_f(acc[m] + b1[m]);
    if (lane < M) {
        float o = b2[lane];
        #pragma unroll
        for (int m = 0; m < M; ++m) o = fmaf(tm[m], W2[m * M + lane], o);
        out[(size_t)n * ldOut + lane] = o;
    }
}

// ---------------------------------------------------------------------------
// Output assembly: out[N][13][3]
// ---------------------------------------------------------------------------
__global__ __launch_bounds__(256) void assemble_kernel(
    const int* __restrict__ z,
    const float* __restrict__ bbde, const float* __restrict__ scde,
    const float* __restrict__ bbA, const float* __restrict__ bbT,
    const float* __restrict__ scA, const float* __restrict__ scT,
    float* __restrict__ out, int N)
{
    int idx = blockIdx.x * 256 + threadIdx.x;
    if (idx >= N * 39) return;
    int n = idx / 39;
    int s = idx - n * 39;
    int row = s / 3;
    int col = s - row * 3;
    float val;
    if (row < 3) {
        if (col == 0)      val = bbde[z[n] * 3 + row];
        else if (col == 1) val = bbA[n * 3 + row];
        else               val = bbT[n * 3 + row];
    } else {
        int r = row - 3;
        if (col == 0)      val = scde[z[n] * 10 + r];
        else if (col == 1) val = scA[n * 10 + r];
        else               val = scT[n * 10 + r];
    }
    out[idx] = val;
}

extern "C" void kernel_launch(void* const* d_in, const int* in_sizes, int n_in,
                              void* d_out, int out_size, void* d_ws, size_t ws_size,
                              hipStream_t stream)
{
    const int*   cg_z        = (const int*)d_in[0];
    const float* cg_xyz      = (const float*)d_in[1];
    const int*   nbr         = (const int*)d_in[2];
    // d_in[3] = mapping (unused by reference)
    const float* S_in        = (const float*)d_in[4];
    const float* res_embed   = (const float*)d_in[5];
    const float* msg_W1      = (const float*)d_in[6];
    const float* msg_b1      = (const float*)d_in[7];
    const float* msg_W2      = (const float*)d_in[8];
    const float* msg_b2      = (const float*)d_in[9];
    const float* dist_W      = (const float*)d_in[10];
    const float* dist_b      = (const float*)d_in[11];
    const float* dense_W1    = (const float*)d_in[12];
    const float* dense_b1    = (const float*)d_in[13];
    const float* dense_W2    = (const float*)d_in[14];
    const float* dense_b2    = (const float*)d_in[15];
    const float* bb_dist_emb = (const float*)d_in[16];
    const float* sc_dist_emb = (const float*)d_in[17];
    const float* bba_W1      = (const float*)d_in[18];
    const float* bba_b1      = (const float*)d_in[19];
    const float* bba_W2      = (const float*)d_in[20];
    const float* bba_b2      = (const float*)d_in[21];
    const float* sca_W1      = (const float*)d_in[22];
    const float* sca_b1      = (const float*)d_in[23];
    const float* sca_W2      = (const float*)d_in[24];
    const float* sca_b2      = (const float*)d_in[25];
    const float* bbt_W1      = (const float*)d_in[26];
    const float* bbt_b1      = (const float*)d_in[27];
    const float* bbt_W2      = (const float*)d_in[28];
    const float* bbt_b2      = (const float*)d_in[29];
    const float* sct_W1      = (const float*)d_in[30];
    const float* sct_b1      = (const float*)d_in[31];
    const float* sct_W2      = (const float*)d_in[32];
    const float* sct_b2      = (const float*)d_in[33];
    const float* ft_W1       = (const float*)d_in[34];
    const float* ft_b1       = (const float*)d_in[35];
    const float* ft_W2       = (const float*)d_in[36];
    const float* ft_b2       = (const float*)d_in[37];

    const int N = in_sizes[0];
    const int E = in_sizes[2] / 2;

    float* ws   = (float*)d_ws;
    float* rbfs = ws;  ws += (size_t)E * 16;   // CSR-sorted, env-premultiplied
    float* envs = ws;  ws += (size_t)E;
    float* S0   = ws;  ws += (size_t)N * 128;
    float* V    = ws;  ws += (size_t)N * 128;
    float* scS  = ws;  ws += (size_t)N * 140;
    float* bbA  = ws;  ws += (size_t)N * 3;
    float* bbT  = ws;  ws += (size_t)N * 3;
    float* scA  = ws;  ws += (size_t)N * 10;
    float* scT  = ws;  ws += (size_t)N * 10;
    __hip_bfloat16* PHI = (__hip_bfloat16*)ws;  ws += (size_t)N * 64;  // N*128 bf16
    int* js     = (int*)ws;  ws = (float*)((int*)ws + E);
    int* eptr   = (int*)ws;  ws = (float*)((int*)ws + (N + 1));
    int* counts = (int*)ws;  ws = (float*)((int*)ws + N);
    int* cursor = (int*)ws;  ws = (float*)((int*)ws + N);

    // CSR build (counts and cursor adjacent -> one memset), then fused
    // geometry + scatter into CSR order.
    (void)hipMemsetAsync(counts, 0, (size_t)2 * N * sizeof(int), stream);
    hist_kernel<<<DIV_UP(E, 256), 256, 0, stream>>>(nbr, counts, E);
    scan_kernel<<<1, 1024, 0, stream>>>(counts, eptr, N);
    geom_scatter_kernel<<<DIV_UP(E, 256), 256, 0, stream>>>(
        nbr, cg_xyz, eptr, cursor, rbfs, envs, js, E);

    concat_s_kernel<<<DIV_UP(N * 128, 256), 256, 0, stream>>>(S_in, res_embed, cg_z, S0, N);

    for (int i = 0; i < 3; ++i) {
        mlp2_kernel<128, false, false, __hip_bfloat16><<<DIV_UP(N, 48), 256, 0, stream>>>(
            S0, 128, msg_W1 + (size_t)i * 128 * 128, msg_b1 + i * 128,
            msg_W2 + (size_t)i * 128 * 128, msg_b2 + i * 128, PHI, 128, N);
        gather_msg_kernel<<<DIV_UP(N, 4), 256, 0, stream>>>(
            eptr, rbfs, envs, js, PHI,
            dist_W + (size_t)i * 16 * 128, dist_b + i * 128, V, N);
        mlp2_kernel<128, true, true, float><<<DIV_UP(N, 48), 256, 0, stream>>>(
            V, 128, dense_W1 + (size_t)i * 128 * 128, dense_b1 + i * 128,
            dense_W2 + (size_t)i * 128 * 128, dense_b2 + i * 128, S0, 128, N);
    }

    head_kernel<3><<<DIV_UP(N, 4), 256, 0, stream>>>(
        S0, 128, 128, S0, 0, 0, bba_W1, bba_b1, bba_W2, bba_b2, bbA, 3, N);
    head_kernel<3><<<DIV_UP(N, 4), 256, 0, stream>>>(
        S0, 128, 128, bbA, 3, 3, bbt_W1, bbt_b1, bbt_W2, bbt_b2, bbT, 3, N);
    head_kernel<10><<<DIV_UP(N, 4), 256, 0, stream>>>(
        S0, 128, 128, S0, 0, 0, sca_W1, sca_b1, sca_W2, sca_b2, scA, 10, N);

    concat_sc_kernel<<<DIV_UP(N * 140, 256), 256, 0, stream>>>(S0, scA, scS, N);
    for (int i = 0; i < 3; ++i) {
        mlp2_kernel<138, true, true, float><<<DIV_UP(N, 48), 256, 0, stream>>>(
            scS, 140, sct_W1 + (size_t)i * 138 * 138, sct_b1 + i * 138,
            sct_W2 + (size_t)i * 138 * 138, sct_b2 + i * 138, scS, 140, N);
    }
    head_kernel<10><<<DIV_UP(N, 4), 256, 0, stream>>>(
        scS, 140, 138, scS, 0, 0, ft_W1, ft_b1, ft_W2, ft_b2, scT, 10, N);

    assemble_kernel<<<DIV_UP(N * 39, 256), 256, 0, stream>>>(
        cg_z, bb_dist_emb, sc_dist_emb, bbA, bbT, scA, scT, (float*)d_out, N);
}

// Round 6
// 824.886 us; speedup vs baseline: 1.7068x; 1.1659x over previous
//
#include <hip/hip_runtime.h>
#include <hip/hip_bf16.h>

#define DIV_UP(a,b) (((a)+(b)-1)/(b))

typedef __attribute__((ext_vector_type(8))) short bf16x8;
typedef __attribute__((ext_vector_type(4))) float f32x4;

__device__ __forceinline__ float silu_f(float x) {
    return x / (1.0f + __expf(-x));
}
__device__ __forceinline__ unsigned short f2bf(float x) {
    __hip_bfloat16 h = __float2bfloat16(x);
    return *reinterpret_cast<unsigned short*>(&h);
}
__device__ __forceinline__ float bf2f(unsigned short u) {
    unsigned int v = (unsigned int)u << 16;
    return __uint_as_float(v);
}
__device__ __forceinline__ void split_bf(float x, unsigned short& hi, unsigned short& lo) {
    hi = f2bf(x);
    lo = f2bf(x - bf2f(hi));
}

#define WSLOT 16384   // 128*128 bf16 elements per weight slot (K=128 only)

// ---------------------------------------------------------------------------
// Weight prep (K=128 MLPs only): f32 [128][128] -> bf16 hi/lo, transposed
// (Wt[c][k] = W[k][c]).  Slot s = kind*3+conv, kinds 0..3: msgW1,msgW2,
// denseW1,denseW2.  hi at WB[(2s)*WSLOT], lo at WB[(2s+1)*WSLOT].
// ---------------------------------------------------------------------------
__global__ __launch_bounds__(256) void prep_weights_kernel(
    const float* __restrict__ msgW1, const float* __restrict__ msgW2,
    const float* __restrict__ denseW1, const float* __restrict__ denseW2,
    unsigned short* __restrict__ WB)
{
    int slot = blockIdx.y;
    int kind = slot / 3, conv = slot % 3;
    const float* base;
    switch (kind) {
        case 0: base = msgW1; break;
        case 1: base = msgW2; break;
        case 2: base = denseW1; break;
        default: base = denseW2; break;
    }
    const float* W = base + (size_t)conv * 128 * 128;
    int idx = blockIdx.x * 256 + threadIdx.x;
    if (idx >= 16384) return;
    int c = idx >> 7, k = idx & 127;
    float val = W[(size_t)k * 128 + c];
    unsigned short hi, lo;
    split_bf(val, hi, lo);
    WB[(size_t)(2 * slot) * WSLOT + idx]     = hi;
    WB[(size_t)(2 * slot + 1) * WSLOT + idx] = lo;
}

// ---------------------------------------------------------------------------
// CSR build: histogram -> single-block scan
// ---------------------------------------------------------------------------
__global__ __launch_bounds__(256) void hist_kernel(
    const int* __restrict__ nbr, int* __restrict__ counts, int E)
{
    int e = blockIdx.x * 256 + threadIdx.x;
    if (e < E) atomicAdd(&counts[nbr[2 * e]], 1);
}

__global__ __launch_bounds__(1024) void scan_kernel(
    const int* __restrict__ counts, int* __restrict__ eptr, int N)
{
    __shared__ int part[1024];
    const int t = threadIdx.x;
    const int chunk = DIV_UP(N, 1024);
    int s = 0;
    for (int c = 0; c < chunk; ++c) {
        int idx = t * chunk + c;
        if (idx < N) s += counts[idx];
    }
    part[t] = s;
    __syncthreads();
    for (int off = 1; off < 1024; off <<= 1) {
        int v = (t >= off) ? part[t - off] : 0;
        __syncthreads();
        part[t] += v;
        __syncthreads();
    }
    int pre = (t > 0) ? part[t - 1] : 0;
    for (int c = 0; c < chunk; ++c) {
        int idx = t * chunk + c;
        if (idx < N) { eptr[idx] = pre; pre += counts[idx]; }
    }
    if (t == 1023) eptr[N] = part[1023];
}

// ---------------------------------------------------------------------------
// Fused edge geometry + CSR scatter.  rbf premultiplied by envelope, stored
// BF16 (16 x bf16 = 32 B per edge); env kept f32 for the bias term.
// ---------------------------------------------------------------------------
__global__ __launch_bounds__(256) void geom_scatter_kernel(
    const int* __restrict__ nbr, const float* __restrict__ xyz,
    const int* __restrict__ eptr, int* __restrict__ cursor,
    unsigned short* __restrict__ rbfs, float* __restrict__ envs,
    int* __restrict__ js, int E)
{
    int e = blockIdx.x * 256 + threadIdx.x;
    if (e >= E) return;
    int i = nbr[2 * e], j = nbr[2 * e + 1];
    float dx = xyz[3 * j + 0] - xyz[3 * i + 0];
    float dy = xyz[3 * j + 1] - xyz[3 * i + 1];
    float dz = xyz[3 * j + 2] - xyz[3 * i + 2];
    float dist = sqrtf(dx * dx + dy * dy + dz * dz);
    float x = dist * 0.3141592653589793f;   // pi/CUTOFF
    float s, c;
    __sincosf(x, &s, &c);
    float env = (dist < 10.0f) ? 0.5f * (c + 1.0f) : 0.0f;
    float inv_env = env / dist;
    float two_c = 2.0f * c;
    float sm1 = 0.0f, s0 = s;
    __align__(16) unsigned short ob[16];
    #pragma unroll
    for (int k = 0; k < 16; ++k) {
        ob[k] = f2bf(s0 * inv_env);
        float s1 = two_c * s0 - sm1;
        sm1 = s0; s0 = s1;
    }
    int p = eptr[i] + atomicAdd(&cursor[i], 1);
    uint4* rp = (uint4*)(rbfs + (size_t)p * 16);
    rp[0] = *(const uint4*)&ob[0];
    rp[1] = *(const uint4*)&ob[8];
    envs[p] = env;
    js[p] = j;
}

// ---------------------------------------------------------------------------
// S0 = concat(S[N,124], res_embed[cg_z][N,4])  -> [N,128]
// ---------------------------------------------------------------------------
__global__ __launch_bounds__(256) void concat_s_kernel(
    const float* __restrict__ S, const float* __restrict__ res_embed,
    const int* __restrict__ z, float* __restrict__ S0, int N)
{
    int idx = blockIdx.x * 256 + threadIdx.x;
    if (idx >= N * 128) return;
    int n = idx >> 7, c = idx & 127;
    float val = (c < 124) ? S[n * 124 + c] : res_embed[z[n] * 4 + (c - 124)];
    S0[idx] = val;
}

// ---------------------------------------------------------------------------
// scS = concat(S0[N,128], scA[N,10]) -> [N,140] (2 pad zeros)
// ---------------------------------------------------------------------------
__global__ __launch_bounds__(256) void concat_sc_kernel(
    const float* __restrict__ S0, const float* __restrict__ scA,
    float* __restrict__ scS, int N)
{
    int idx = blockIdx.x * 256 + threadIdx.x;
    if (idx >= N * 140) return;
    int n = idx / 140, c = idx - n * 140;
    float val = 0.0f;
    if (c < 128)       val = S0[n * 128 + c];
    else if (c < 138)  val = scA[n * 10 + (c - 128)];
    scS[idx] = val;
}

// ---------------------------------------------------------------------------
// Split-bf16 MFMA two-stage MLP, K=128 only, LDS <= 56 KB:
//   Y (+=) silu(f_in(X) @ W1 + b1) @ W2 + b2
// X split hi+lo resident in LDS; W hi and lo streamed through ONE buffer:
//   pass A (WS=Whi): acc += Ahi*Whi + Alo*Whi;  pass B (WS=Wlo): acc += Ahi*Wlo
// (drops only the 2^-18-relative lo*lo term -> ~fp32 precision).
// LDS XOR-swizzle ((row&7)<<4 on byte offset) -> conflict-free ds_read_b128.
// Frag layout (m89/m97): A/B lane l: row/col=l&15, k=8*(l>>4)+i;
// D lane l reg i: row=(l>>4)*4+i, col=l&15.
// ---------------------------------------------------------------------------
template<int MT, bool PREACT, bool RESID, typename OutT>
__global__ __launch_bounds__(256) void mlp2_mfma_kernel(
    const float* __restrict__ X,
    const unsigned short* __restrict__ W1hi, const unsigned short* __restrict__ W1lo,
    const float* __restrict__ b1,
    const unsigned short* __restrict__ W2hi, const unsigned short* __restrict__ W2lo,
    const float* __restrict__ b2,
    OutT* __restrict__ Y, int nrows)
{
    constexpr int RB   = MT / 16;     // row-blocks (3 for MT=48)
    constexpr int ROWB = 256;         // bytes per LDS row (128 bf16)
    __shared__ __align__(16) unsigned short XHhi[MT * 128];
    __shared__ __align__(16) unsigned short XHlo[MT * 128];
    __shared__ __align__(16) unsigned short WS[128 * 128];

    const int tid  = threadIdx.x;
    const int wave = tid >> 6;
    const int lane = tid & 63;
    const int l15  = lane & 15;
    const int kg   = lane >> 4;
    const int row0 = blockIdx.x * MT;

    // ---- stage X: f32 -> (silu) -> hi/lo bf16, swizzled ----
    for (int idx = tid; idx < MT * 32; idx += 256) {
        int r = idx >> 5, q = idx & 31;
        int gr = row0 + r;
        float4 xv = make_float4(0.f, 0.f, 0.f, 0.f);
        if (gr < nrows) xv = *(const float4*)(X + (size_t)gr * 128 + 4 * q);
        if (PREACT) { xv.x = silu_f(xv.x); xv.y = silu_f(xv.y);
                      xv.z = silu_f(xv.z); xv.w = silu_f(xv.w); }
        ushort4 h, l;
        split_bf(xv.x, h.x, l.x); split_bf(xv.y, h.y, l.y);
        split_bf(xv.z, h.z, l.z); split_bf(xv.w, h.w, l.w);
        int off = (8 * q) ^ ((r & 7) << 4);
        *(ushort4*)((char*)XHhi + r * ROWB + off) = h;
        *(ushort4*)((char*)XHlo + r * ROWB + off) = l;
    }

    f32x4 acc[RB][2];

    #define STAGE_W(WPTR)                                                       \
        for (int idx = tid; idx < 2048; idx += 256) {                           \
            int r = idx >> 4;                                                   \
            int byt = (idx & 15) * 16;                                          \
            *(uint4*)((char*)WS + r * ROWB + (byt ^ ((r & 7) << 4))) =          \
                *(const uint4*)((WPTR) + (size_t)idx * 8);                      \
        }

    #define PASS(WITH_LO)                                                       \
        _Pragma("unroll")                                                       \
        for (int kk = 0; kk < 4; ++kk) {                                        \
            const int kbyte = kk * 64 + kg * 16;                                \
            bf16x8 ah[RB], al[RB];                                              \
            _Pragma("unroll")                                                   \
            for (int rb = 0; rb < RB; ++rb) {                                   \
                int r = 16 * rb + l15;                                          \
                int off = kbyte ^ ((r & 7) << 4);                               \
                ah[rb] = *(const bf16x8*)((const char*)XHhi + r * ROWB + off);  \
                if (WITH_LO)                                                    \
                    al[rb] = *(const bf16x8*)((const char*)XHlo + r * ROWB + off); \
            }                                                                   \
            _Pragma("unroll")                                                   \
            for (int cbi = 0; cbi < 2; ++cbi) {                                 \
                int rw = 16 * (wave + 4 * cbi) + l15;                           \
                int offw = kbyte ^ ((rw & 7) << 4);                             \
                bf16x8 bw = *(const bf16x8*)((const char*)WS + rw * ROWB + offw); \
                _Pragma("unroll")                                               \
                for (int rb = 0; rb < RB; ++rb) {                               \
                    f32x4 t = acc[rb][cbi];                                     \
                    t = __builtin_amdgcn_mfma_f32_16x16x32_bf16(ah[rb], bw, t, 0, 0, 0); \
                    if (WITH_LO)                                                \
                        t = __builtin_amdgcn_mfma_f32_16x16x32_bf16(al[rb], bw, t, 0, 0, 0); \
                    acc[rb][cbi] = t;                                           \
                }                                                               \
            }                                                                   \
        }

    // ================= stage 1: X @ W1 =================
    #pragma unroll
    for (int a = 0; a < RB; ++a) { acc[a][0] = (f32x4){0,0,0,0}; acc[a][1] = (f32x4){0,0,0,0}; }
    STAGE_W(W1hi)
    __syncthreads();
    PASS(true)           // Ahi*W1hi + Alo*W1hi
    __syncthreads();
    STAGE_W(W1lo)
    __syncthreads();
    PASS(false)          // Ahi*W1lo
    __syncthreads();

    // ---- H = silu(acc + b1) -> XH hi/lo (swizzled); stage W2hi ----
    #pragma unroll
    for (int cbi = 0; cbi < 2; ++cbi) {
        int col = 16 * (wave + 4 * cbi) + l15;
        float b1v = b1[col];
        #pragma unroll
        for (int rb = 0; rb < RB; ++rb)
            #pragma unroll
            for (int i = 0; i < 4; ++i) {
                int r = 16 * rb + kg * 4 + i;
                float h = silu_f(acc[rb][cbi][i] + b1v);
                unsigned short hh, hl;
                split_bf(h, hh, hl);
                int off = (2 * col) ^ ((r & 7) << 4);
                *(unsigned short*)((char*)XHhi + r * ROWB + off) = hh;
                *(unsigned short*)((char*)XHlo + r * ROWB + off) = hl;
            }
    }
    // ================= stage 2: H @ W2 =================
    #pragma unroll
    for (int a = 0; a < RB; ++a) { acc[a][0] = (f32x4){0,0,0,0}; acc[a][1] = (f32x4){0,0,0,0}; }
    STAGE_W(W2hi)
    __syncthreads();
    PASS(true)
    __syncthreads();
    STAGE_W(W2lo)
    __syncthreads();
    PASS(false)
    #undef PASS
    #undef STAGE_W

    // ---- epilogue: Y (+=) acc + b2 ----
    #pragma unroll
    for (int cbi = 0; cbi < 2; ++cbi) {
        int col = 16 * (wave + 4 * cbi) + l15;
        float b2v = b2[col];
        #pragma unroll
        for (int rb = 0; rb < RB; ++rb)
            #pragma unroll
            for (int i = 0; i < 4; ++i) {
                int gr = row0 + 16 * rb + kg * 4 + i;
                if (gr < nrows) {
                    size_t off = (size_t)gr * 128 + col;
                    float val = acc[rb][cbi][i] + b2v;
                    if (RESID) val += (float)Y[off];
                    if constexpr (sizeof(OutT) == 2)
                        Y[off] = __float2bfloat16(val);
                    else
                        Y[off] = val;
                }
            }
    }
}

// ---------------------------------------------------------------------------
// Generic two-stage fp32 MLP (r3-proven), used for the K=138 sct layers.
// ---------------------------------------------------------------------------
template<int K, bool PREACT, bool RESID, typename OutT>
__global__ __launch_bounds__(256) void mlp2_kernel(
    const float* __restrict__ X, int ldX,
    const float* __restrict__ W1, const float* __restrict__ b1,
    const float* __restrict__ W2, const float* __restrict__ b2,
    OutT* __restrict__ Y, int ldY, int nrows)
{
    constexpr int NC = (K + 31) / 32;
    constexpr int ROWS = 48;
    constexpr int RR = 6;
    __shared__ float Xs[ROWS * K];
    __shared__ float Hs[ROWS * K];
    const int tid = threadIdx.x;
    const int row0 = blockIdx.x * ROWS;

    for (int idx = tid; idx < ROWS * K; idx += 256) {
        int r = idx / K, c = idx - r * K;
        int gr = row0 + r;
        float x = (gr < nrows) ? X[(size_t)gr * ldX + c] : 0.0f;
        if (PREACT) x = silu_f(x);
        Xs[idx] = x;
    }
    __syncthreads();

    const int cc = tid & 31;
    const int r0 = (tid >> 5) * RR;

    float acc[NC][RR];
    #pragma unroll
    for (int jc = 0; jc < NC; ++jc) {
        int col = cc + 32 * jc;
        float bv = (col < K) ? b1[col] : 0.0f;
        #pragma unroll
        for (int rr = 0; rr < RR; ++rr) acc[jc][rr] = bv;
    }
    for (int k = 0; k < K; ++k) {
        float w[NC];
        #pragma unroll
        for (int jc = 0; jc < NC; ++jc) {
            int col = cc + 32 * jc;
            w[jc] = (col < K) ? W1[k * K + col] : 0.0f;
        }
        float xv[RR];
        #pragma unroll
        for (int rr = 0; rr < RR; ++rr) xv[rr] = Xs[(r0 + rr) * K + k];
        #pragma unroll
        for (int jc = 0; jc < NC; ++jc)
            #pragma unroll
            for (int rr = 0; rr < RR; ++rr)
                acc[jc][rr] = fmaf(xv[rr], w[jc], acc[jc][rr]);
    }
    #pragma unroll
    for (int jc = 0; jc < NC; ++jc) {
        int col = cc + 32 * jc;
        if (col < K) {
            #pragma unroll
            for (int rr = 0; rr < RR; ++rr)
                Hs[(r0 + rr) * K + col] = silu_f(acc[jc][rr]);
        }
    }
    __syncthreads();

    #pragma unroll
    for (int jc = 0; jc < NC; ++jc) {
        int col = cc + 32 * jc;
        float bv = (col < K) ? b2[col] : 0.0f;
        #pragma unroll
        for (int rr = 0; rr < RR; ++rr) acc[jc][rr] = bv;
    }
    for (int k = 0; k < K; ++k) {
        float w[NC];
        #pragma unroll
        for (int jc = 0; jc < NC; ++jc) {
            int col = cc + 32 * jc;
            w[jc] = (col < K) ? W2[k * K + col] : 0.0f;
        }
        float xv[RR];
        #pragma unroll
        for (int rr = 0; rr < RR; ++rr) xv[rr] = Hs[(r0 + rr) * K + k];
        #pragma unroll
        for (int jc = 0; jc < NC; ++jc)
            #pragma unroll
            for (int rr = 0; rr < RR; ++rr)
                acc[jc][rr] = fmaf(xv[rr], w[jc], acc[jc][rr]);
    }
    #pragma unroll
    for (int jc = 0; jc < NC; ++jc) {
        int col = cc + 32 * jc;
        if (col < K) {
            #pragma unroll
            for (int rr = 0; rr < RR; ++rr) {
                int gr = row0 + r0 + rr;
                if (gr < nrows) {
                    size_t off = (size_t)gr * ldY + col;
                    float val = acc[jc][rr];
                    if (RESID) val += (float)Y[off];
                    if constexpr (sizeof(OutT) == 2)
                        Y[off] = __float2bfloat16(val);
                    else
                        Y[off] = val;
                }
            }
        }
    }
}

// ---------------------------------------------------------------------------
// Gathered edge message + segment sum over CSR-sorted streaming edge records.
// TWO waves per node; lane owns one col c = 64*half + lane.  4-edge unroll,
// 4 independent accumulators, 4-way split dot chains.  rbf is bf16.
// ---------------------------------------------------------------------------
__device__ __forceinline__ void unpack16(uint4 a, uint4 b, float* r) {
    const unsigned int* u = (const unsigned int*)&a;
    #pragma unroll
    for (int w = 0; w < 4; ++w) {
        r[2 * w]     = __uint_as_float(u[w] << 16);
        r[2 * w + 1] = __uint_as_float(u[w] & 0xffff0000u);
    }
    const unsigned int* v = (const unsigned int*)&b;
    #pragma unroll
    for (int w = 0; w < 4; ++w) {
        r[8 + 2 * w]     = __uint_as_float(v[w] << 16);
        r[8 + 2 * w + 1] = __uint_as_float(v[w] & 0xffff0000u);
    }
}

__device__ __forceinline__ float wdot16a(const float* r, const float* dw, float init) {
    float t0 = fmaf(r[0], dw[0], init);
    t0 = fmaf(r[1], dw[1], t0); t0 = fmaf(r[2], dw[2], t0); t0 = fmaf(r[3], dw[3], t0);
    float t1 = r[4] * dw[4];
    t1 = fmaf(r[5], dw[5], t1); t1 = fmaf(r[6], dw[6], t1); t1 = fmaf(r[7], dw[7], t1);
    float t2 = r[8] * dw[8];
    t2 = fmaf(r[9], dw[9], t2); t2 = fmaf(r[10], dw[10], t2); t2 = fmaf(r[11], dw[11], t2);
    float t3 = r[12] * dw[12];
    t3 = fmaf(r[13], dw[13], t3); t3 = fmaf(r[14], dw[14], t3); t3 = fmaf(r[15], dw[15], t3);
    return (t0 + t1) + (t2 + t3);
}

__global__ __launch_bounds__(256) void gather_msg_kernel(
    const int* __restrict__ eptr,
    const unsigned short* __restrict__ rbfs, const float* __restrict__ envs,
    const int* __restrict__ js,
    const __hip_bfloat16* __restrict__ phi,
    const float* __restrict__ distW, const float* __restrict__ distb,
    float* __restrict__ v, int N)
{
    const int w = blockIdx.x * 4 + (threadIdx.x >> 6);
    const int lane = threadIdx.x & 63;
    const int n = w >> 1;
    if (n >= N) return;
    const int c = ((w & 1) << 6) | lane;

    float dw[16];
    #pragma unroll
    for (int k = 0; k < 16; ++k) dw[k] = distW[k * 128 + c];
    const float db = distb[c];

    float a0 = 0.f, a1 = 0.f, a2 = 0.f, a3 = 0.f;
    const int p0 = eptr[n], p1 = eptr[n + 1];
    int p = p0;
    for (; p + 4 <= p1; p += 4) {
        const int j0 = js[p], j1 = js[p + 1], j2 = js[p + 2], j3 = js[p + 3];
        const float e0 = envs[p], e1 = envs[p + 1], e2 = envs[p + 2], e3 = envs[p + 3];
        const uint4* q = (const uint4*)(rbfs + (size_t)p * 16);
        float f0 = __bfloat162float(phi[(size_t)j0 * 128 + c]);
        float f1 = __bfloat162float(phi[(size_t)j1 * 128 + c]);
        float f2 = __bfloat162float(phi[(size_t)j2 * 128 + c]);
        float f3 = __bfloat162float(phi[(size_t)j3 * 128 + c]);
        float r[16];
        unpack16(q[0], q[1], r);
        a0 = fmaf(wdot16a(r, dw, db * e0), f0, a0);
        unpack16(q[2], q[3], r);
        a1 = fmaf(wdot16a(r, dw, db * e1), f1, a1);
        unpack16(q[4], q[5], r);
        a2 = fmaf(wdot16a(r, dw, db * e2), f2, a2);
        unpack16(q[6], q[7], r);
        a3 = fmaf(wdot16a(r, dw, db * e3), f3, a3);
    }
    for (; p < p1; ++p) {
        const int jj = js[p];
        const float ev = envs[p];
        const uint4* q = (const uint4*)(rbfs + (size_t)p * 16);
        float f = __bfloat162float(phi[(size_t)jj * 128 + c]);
        float r[16];
        unpack16(q[0], q[1], r);
        a0 = fmaf(wdot16a(r, dw, db * ev), f, a0);
    }
    v[(size_t)n * 128 + c] = (a0 + a1) + (a2 + a3);
}

// ---------------------------------------------------------------------------
// Small head: out = silu( silu(x) @ W1 + b1 ) @ W2 + b2   (final linear, no act)
// ---------------------------------------------------------------------------
template<int M>
__global__ __launch_bounds__(256) void head_kernel(
    const float* __restrict__ X, int ldX, int K1,
    const float* __restrict__ X2, int ldX2, int K2,
    const float* __restrict__ W1, const float* __restrict__ b1,
    const float* __restrict__ W2, const float* __restrict__ b2,
    float* __restrict__ out, int ldOut, int nrows)
{
    const int wid = threadIdx.x >> 6;
    const int lane = threadIdx.x & 63;
    const int n = blockIdx.x * 4 + wid;
    if (n >= nrows) return;
    const int K = K1 + K2;
    float sx[3];
    #pragma unroll
    for (int t = 0; t < 3; ++t) {
        int k = lane + 64 * t;
        float v = 0.0f;
        if (k < K1) v = X[(size_t)n * ldX + k];
        else if (k < K) v = X2[(size_t)n * ldX2 + (k - K1)];
        sx[t] = (k < K) ? silu_f(v) : 0.0f;
    }
    float acc[M];
    #pragma unroll
    for (int m = 0; m < M; ++m) {
        float a = 0.0f;
        #pragma unroll
        for (int t = 0; t < 3; ++t) {
            int k = lane + 64 * t;
            if (k < K) a = fmaf(sx[t], W1[k * M + m], a);
        }
        acc[m] = a;
    }
    #pragma unroll
    for (int m = 0; m < M; ++m) {
        #pragma unroll
        for (int off = 32; off > 0; off >>= 1)
            acc[m] += __shfl_xor(acc[m], off, 64);
    }
    float tm[M];
    #pragma unroll
    for (int m = 0; m < M; ++m) tm[m] = silu_f(acc[m] + b1[m]);
    if (lane < M) {
        float o = b2[lane];
        #pragma unroll
        for (int m = 0; m < M; ++m) o = fmaf(tm[m], W2[m * M + lane], o);
        out[(size_t)n * ldOut + lane] = o;
    }
}

// ---------------------------------------------------------------------------
// Output assembly: out[N][13][3]
// ---------------------------------------------------------------------------
__global__ __launch_bounds__(256) void assemble_kernel(
    const int* __restrict__ z,
    const float* __restrict__ bbde, const float* __restrict__ scde,
    const float* __restrict__ bbA, const float* __restrict__ bbT,
    const float* __restrict__ scA, const float* __restrict__ scT,
    float* __restrict__ out, int N)
{
    int idx = blockIdx.x * 256 + threadIdx.x;
    if (idx >= N * 39) return;
    int n = idx / 39;
    int s = idx - n * 39;
    int row = s / 3;
    int col = s - row * 3;
    float val;
    if (row < 3) {
        if (col == 0)      val = bbde[z[n] * 3 + row];
        else if (col == 1) val = bbA[n * 3 + row];
        else               val = bbT[n * 3 + row];
    } else {
        int r = row - 3;
        if (col == 0)      val = scde[z[n] * 10 + r];
        else if (col == 1) val = scA[n * 10 + r];
        else               val = scT[n * 10 + r];
    }
    out[idx] = val;
}

extern "C" void kernel_launch(void* const* d_in, const int* in_sizes, int n_in,
                              void* d_out, int out_size, void* d_ws, size_t ws_size,
                              hipStream_t stream)
{
    const int*   cg_z        = (const int*)d_in[0];
    const float* cg_xyz      = (const float*)d_in[1];
    const int*   nbr         = (const int*)d_in[2];
    // d_in[3] = mapping (unused by reference)
    const float* S_in        = (const float*)d_in[4];
    const float* res_embed   = (const float*)d_in[5];
    const float* msg_W1      = (const float*)d_in[6];
    const float* msg_b1      = (const float*)d_in[7];
    const float* msg_W2      = (const float*)d_in[8];
    const float* msg_b2      = (const float*)d_in[9];
    const float* dist_W      = (const float*)d_in[10];
    const float* dist_b      = (const float*)d_in[11];
    const float* dense_W1    = (const float*)d_in[12];
    const float* dense_b1    = (const float*)d_in[13];
    const float* dense_W2    = (const float*)d_in[14];
    const float* dense_b2    = (const float*)d_in[15];
    const float* bb_dist_emb = (const float*)d_in[16];
    const float* sc_dist_emb = (const float*)d_in[17];
    const float* bba_W1      = (const float*)d_in[18];
    const float* bba_b1      = (const float*)d_in[19];
    const float* bba_W2      = (const float*)d_in[20];
    const float* bba_b2      = (const float*)d_in[21];
    const float* sca_W1      = (const float*)d_in[22];
    const float* sca_b1      = (const float*)d_in[23];
    const float* sca_W2      = (const float*)d_in[24];
    const float* sca_b2      = (const float*)d_in[25];
    const float* bbt_W1      = (const float*)d_in[26];
    const float* bbt_b1      = (const float*)d_in[27];
    const float* bbt_W2      = (const float*)d_in[28];
    const float* bbt_b2      = (const float*)d_in[29];
    const float* sct_W1      = (const float*)d_in[30];
    const float* sct_b1      = (const float*)d_in[31];
    const float* sct_W2      = (const float*)d_in[32];
    const float* sct_b2      = (const float*)d_in[33];
    const float* ft_W1       = (const float*)d_in[34];
    const float* ft_b1       = (const float*)d_in[35];
    const float* ft_W2       = (const float*)d_in[36];
    const float* ft_b2       = (const float*)d_in[37];

    const int N = in_sizes[0];
    const int E = in_sizes[2] / 2;

    unsigned short* WB   = (unsigned short*)d_ws;                      // 24*WSLOT bf16
    unsigned short* rbfs = WB + (size_t)24 * WSLOT;                    // E*16 bf16
    float* ws   = (float*)(rbfs + (size_t)E * 16);
    float* envs = ws;  ws += (size_t)E;
    float* S0   = ws;  ws += (size_t)N * 128;
    float* V    = ws;  ws += (size_t)N * 128;
    float* scS  = ws;  ws += (size_t)N * 140;
    float* bbA  = ws;  ws += (size_t)N * 3;
    float* bbT  = ws;  ws += (size_t)N * 3;
    float* scA  = ws;  ws += (size_t)N * 10;
    float* scT  = ws;  ws += (size_t)N * 10;
    __hip_bfloat16* PHI = (__hip_bfloat16*)ws;  ws += (size_t)N * 64;  // N*128 bf16
    int* js     = (int*)ws;  ws = (float*)((int*)ws + E);
    int* eptr   = (int*)ws;  ws = (float*)((int*)ws + (N + 1));
    int* counts = (int*)ws;  ws = (float*)((int*)ws + N);
    int* cursor = (int*)ws;  ws = (float*)((int*)ws + N);

    // Weight prep (hi/lo split, transposed) for the K=128 MLPs
    prep_weights_kernel<<<dim3(64, 12), 256, 0, stream>>>(
        msg_W1, msg_W2, dense_W1, dense_W2, WB);

    // CSR build (counts and cursor adjacent -> one memset), then fused
    // geometry + scatter into CSR order.
    (void)hipMemsetAsync(counts, 0, (size_t)2 * N * sizeof(int), stream);
    hist_kernel<<<DIV_UP(E, 256), 256, 0, stream>>>(nbr, counts, E);
    scan_kernel<<<1, 1024, 0, stream>>>(counts, eptr, N);
    geom_scatter_kernel<<<DIV_UP(E, 256), 256, 0, stream>>>(
        nbr, cg_xyz, eptr, cursor, rbfs, envs, js, E);

    concat_s_kernel<<<DIV_UP(N * 128, 256), 256, 0, stream>>>(S_in, res_embed, cg_z, S0, N);

    #define WHI(kind, conv) (WB + (size_t)(2 * ((kind) * 3 + (conv))) * WSLOT)
    #define WLO(kind, conv) (WB + (size_t)(2 * ((kind) * 3 + (conv)) + 1) * WSLOT)

    for (int i = 0; i < 3; ++i) {
        mlp2_mfma_kernel<48, false, false, __hip_bfloat16>
            <<<DIV_UP(N, 48), 256, 0, stream>>>(
            S0, WHI(0, i), WLO(0, i), msg_b1 + i * 128,
            WHI(1, i), WLO(1, i), msg_b2 + i * 128, PHI, N);
        gather_msg_kernel<<<DIV_UP(2 * N, 4), 256, 0, stream>>>(
            eptr, rbfs, envs, js, PHI,
            dist_W + (size_t)i * 16 * 128, dist_b + i * 128, V, N);
        mlp2_mfma_kernel<48, true, true, float>
            <<<DIV_UP(N, 48), 256, 0, stream>>>(
            V, WHI(2, i), WLO(2, i), dense_b1 + i * 128,
            WHI(3, i), WLO(3, i), dense_b2 + i * 128, S0, N);
    }

    head_kernel<3><<<DIV_UP(N, 4), 256, 0, stream>>>(
        S0, 128, 128, S0, 0, 0, bba_W1, bba_b1, bba_W2, bba_b2, bbA, 3, N);
    head_kernel<3><<<DIV_UP(N, 4), 256, 0, stream>>>(
        S0, 128, 128, bbA, 3, 3, bbt_W1, bbt_b1, bbt_W2, bbt_b2, bbT, 3, N);
    head_kernel<10><<<DIV_UP(N, 4), 256, 0, stream>>>(
        S0, 128, 128, S0, 0, 0, sca_W1, sca_b1, sca_W2, sca_b2, scA, 10, N);

    concat_sc_kernel<<<DIV_UP(N * 140, 256), 256, 0, stream>>>(S0, scA, scS, N);
    for (int i = 0; i < 3; ++i) {
        mlp2_kernel<138, true, true, float><<<DIV_UP(N, 48), 256, 0, stream>>>(
            scS, 140, sct_W1 + (size_t)i * 138 * 138, sct_b1 + i * 138,
            sct_W2 + (size_t)i * 138 * 138, sct_b2 + i * 138, scS, 140, N);
    }
    head_kernel<10><<<DIV_UP(N, 4), 256, 0, stream>>>(
        scS, 140, 138, scS, 0, 0, ft_W1, ft_b1, ft_W2, ft_b2, scT, 10, N);

    assemble_kernel<<<DIV_UP(N * 39, 256), 256, 0, stream>>>(
        cg_z, bb_dist_emb, sc_dist_emb, bbA, bbT, scA, scT, (float*)d_out, N);

    #undef WHI
    #undef WLO
}